// Round 9
// baseline (97.763 us; speedup 1.0000x reference)
//
#include <hip/hip_runtime.h>

#define BB 4
#define NN 4096

typedef __attribute__((ext_vector_type(8))) short short8v;   // 8 bf16 = 4 VGPRs
typedef __attribute__((ext_vector_type(4))) short short4v;   // 4 bf16 = 2 VGPRs
typedef __attribute__((ext_vector_type(4))) float float4v;   // MFMA acc

__device__ __forceinline__ unsigned short f2bf_rn(float f) {
    unsigned u = __float_as_uint(f);
    u += 0x7FFFu + ((u >> 16) & 1u);          // round-to-nearest-even
    return (unsigned short)(u >> 16);
}

// pack two fp32 -> one u32 holding {hi: bf16(fb), lo: bf16(fa)}, RTE.
// 2x(v_bfe+v_add3) + v_perm = 5 VALU ops.
__device__ __forceinline__ unsigned pack2_rte(float fa, float fb) {
    unsigned a = __float_as_uint(fa), b = __float_as_uint(fb);
    a = a + 0x7FFFu + ((a >> 16) & 1u);
    b = b + 0x7FFFu + ((b >> 16) & 1u);
    return __builtin_amdgcn_perm(b, a, 0x07060302u);  // {b[31:16], a[31:16]}
}

// ---------------------------------------------------------------------------
// Kernel 1: fused QKV projection, scalar-broadcast GEMM, n-tile 32.
// Outputs: Qt[b][n][8], Kt[b][n][8] (16 B rows); Vsw 1 KB chunks per
// (b,ct,nb): elem[lane*8+j] = V[ct*16+(lane&15)][nb*32+(lane>>4)*8+j].
// ---------------------------------------------------------------------------
__global__ __launch_bounds__(256) void qkv_kernel(
    const float* __restrict__ x,
    const float* __restrict__ Wq, const float* __restrict__ Wk,
    const float* __restrict__ Wv,
    unsigned short* __restrict__ Qt, unsigned short* __restrict__ Kt,
    unsigned short* __restrict__ Vsw)
{
    __shared__ float xs[64][36];
    __shared__ float wl[64][81];
    __shared__ unsigned short Ot[80][40];

    const int t  = threadIdx.x;
    const int b  = blockIdx.y;
    const int nb = blockIdx.x;
    const int n0 = nb * 32;

    #pragma unroll
    for (int i = 0; i < 20; ++i) {
        int idx = t + 256 * i;
        int r = idx >> 6, c = idx & 63;
        float w;
        if (r < 8)       w = Wq[r * 64 + c];
        else if (r < 16) w = Wk[(r - 8) * 64 + c];
        else             w = Wv[(r - 16) * 64 + c];
        wl[c][r] = w;
    }
    #pragma unroll
    for (int i = 0; i < 2; ++i) {
        int idx = t + 256 * i;
        int c = idx >> 3, n4 = (idx & 7) * 4;
        *(float4*)&xs[c][n4] = *(const float4*)&x[(size_t)(b * 64 + c) * NN + n0 + n4];
    }
    __syncthreads();

    const int n2 = (t & 15) * 2;
    const int og = t >> 4;

    float acc[5][2];
    #pragma unroll
    for (int k = 0; k < 5; ++k) { acc[k][0] = 0.f; acc[k][1] = 0.f; }

    for (int c = 0; c < 64; ++c) {
        float2 xv = *(const float2*)&xs[c][n2];
        #pragma unroll
        for (int k = 0; k < 5; ++k) {
            float wv = wl[c][og * 5 + k];
            acc[k][0] += wv * xv.x;
            acc[k][1] += wv * xv.y;
        }
    }

    #pragma unroll
    for (int k = 0; k < 5; ++k) {
        Ot[og * 5 + k][n2]     = f2bf_rn(acc[k][0]);
        Ot[og * 5 + k][n2 + 1] = f2bf_rn(acc[k][1]);
    }
    __syncthreads();

    if (t < 64) {
        int n = t & 31;
        int rbase = (t < 32) ? 0 : 8;
        short8v p;
        #pragma unroll
        for (int j = 0; j < 8; ++j) p[j] = (short)Ot[rbase + j][n];
        unsigned short* dst = ((t < 32) ? Qt : Kt) + ((size_t)b * NN + n0 + n) * 8;
        *(short8v*)dst = p;
    }

    {
        int ct = t >> 6, l = t & 63;
        unsigned short* cb = Vsw + ((size_t)(b * 4 + ct) * 128 + nb) * 512;
        short8v d = *(short8v*)&Ot[16 + ct * 16 + (l & 15)][(l >> 4) * 8];
        *(short8v*)(cb + l * 8) = d;
    }
}

// ---------------------------------------------------------------------------
// Kernel 2: MFMA streaming attention — DECOUPLED DS streams.
// Key fix vs r5-r8: LDS ops retire IN ORDER, so issuing ds_write(chunk i+1)
// before ds_read bp(chunk i) re-serialized every "pipelined" variant (the
// read's wait forced the writes -- and their whole exp/score chain -- to
// complete first). Here bp is read at the TOP of the iteration, before any
// write: PV(i) then only needs lgkmcnt(2) and runs concurrent with the
// score/exp/pack stream of chunk i+1.
// Shape: r6 framing -- grid (256,4) = 1024 blocks (4/CU), block = 4 indep
// waves, wave w owns n in [w*1024,(w+1)*1024), 32 chunks of 32. Pb/Ored
// share one LDS union (17.8 KB -> LDS never caps occupancy); barrier before
// the Ored dump protects the aliasing. No max-subtraction (logits <= ~3).
// ---------------------------------------------------------------------------
union AttnSmem {
    unsigned short Pb[4][2][16][40];   // [wave][dbuf][m][n] bf16, 80 B rows
    float Ored[4][64][17];             // [wave][c][m] fp32 partials
};

__global__ __launch_bounds__(256, 4) void attn_kernel(
    const unsigned short* __restrict__ Qt,
    const unsigned short* __restrict__ Kt,
    const unsigned short* __restrict__ Vsw,
    const float* __restrict__ x, const float* __restrict__ gamma,
    float* __restrict__ out)
{
    __shared__ __align__(16) AttnSmem sm;
    __shared__ float Lred[4][16];
    __shared__ float Lf[16];

    const int t    = threadIdx.x;
    const int w    = t >> 6;
    const int lane = t & 63;
    const int quad = lane >> 4;
    const int l15  = lane & 15;
    const int b    = blockIdx.y;
    const int m0   = blockIdx.x * 16;

    const short8v zfrag = {0, 0, 0, 0, 0, 0, 0, 0};
    const float4v zacc  = {0.f, 0.f, 0.f, 0.f};

    // K-side B fragment (quad0 = real K, K=8 zero-pad)
    short8v bk = zfrag;
    if (quad == 0)
        bk = *(const short8v*)(Kt + (size_t)(b * NN + m0 + l15) * 8);

    float4v acc[4];
    #pragma unroll
    for (int ct = 0; ct < 4; ++ct) acc[ct] = zacc;
    float Lacc = 0.f;

    const unsigned short* qrow = Qt + (size_t)(b * NN + w * 1024 + l15) * 8;
    const unsigned short* vptr = Vsw + ((size_t)b * 4 * 128 + w * 32) * 512 + lane * 8;

    // ---- prolog: chunk 0 scores -> Pb[0]; V(0)->av, V(1)->avn, Q(1)->aqn
    short8v av0 = *(const short8v*)(vptr);
    short8v av1 = *(const short8v*)(vptr + 1 * 128 * 512);
    short8v av2 = *(const short8v*)(vptr + 2 * 128 * 512);
    short8v av3 = *(const short8v*)(vptr + 3 * 128 * 512);
    {
        short8v aq0 = zfrag, aq1 = zfrag;
        if (quad == 0) {
            aq0 = *(const short8v*)(qrow);
            aq1 = *(const short8v*)(qrow + 16 * 8);
        }
        float4v s0 = __builtin_amdgcn_mfma_f32_16x16x32_bf16(aq0, bk, zacc, 0, 0, 0);
        float4v s1 = __builtin_amdgcn_mfma_f32_16x16x32_bf16(aq1, bk, zacc, 0, 0, 0);
        float p[8];
        #pragma unroll
        for (int j = 0; j < 4; ++j) { p[j] = __expf(s0[j]); p[4 + j] = __expf(s1[j]); }
        #pragma unroll
        for (int j = 0; j < 8; ++j) Lacc += p[j];
        unsigned pk0 = pack2_rte(p[0], p[1]), pk1 = pack2_rte(p[2], p[3]);
        unsigned pk2 = pack2_rte(p[4], p[5]), pk3 = pack2_rte(p[6], p[7]);
        *(uint2*)&sm.Pb[w][0][l15][quad * 4]      = make_uint2(pk0, pk1);
        *(uint2*)&sm.Pb[w][0][l15][16 + quad * 4] = make_uint2(pk2, pk3);
    }
    short8v avn0 = *(const short8v*)(vptr + 512);
    short8v avn1 = *(const short8v*)(vptr + 1 * 128 * 512 + 512);
    short8v avn2 = *(const short8v*)(vptr + 2 * 128 * 512 + 512);
    short8v avn3 = *(const short8v*)(vptr + 3 * 128 * 512 + 512);
    short8v aqn0 = zfrag, aqn1 = zfrag;
    if (quad == 0) {
        aqn0 = *(const short8v*)(qrow + 32 * 8);
        aqn1 = *(const short8v*)(qrow + 48 * 8);
    }

    for (int it = 0; it < 31; ++it) {
        const int itn = it + 1;
        const int i2  = (it + 2) & 31;   // wrap: harmless redundant load

        // ---- B-stream head: read bp(it) BEFORE any ds_write this iter
        short8v bp = *(const short8v*)&sm.Pb[w][it & 1][l15][quad * 8];

        // ---- A-stream: scores for chunk itn from prefetched regs
        float4v s0 = __builtin_amdgcn_mfma_f32_16x16x32_bf16(aqn0, bk, zacc, 0, 0, 0);
        float4v s1 = __builtin_amdgcn_mfma_f32_16x16x32_bf16(aqn1, bk, zacc, 0, 0, 0);

        // kick chunk it+2 loads (consumed next iter)
        short8v a2q0 = zfrag, a2q1 = zfrag;
        if (quad == 0) {
            a2q0 = *(const short8v*)(qrow + (size_t)(i2 * 32) * 8);
            a2q1 = *(const short8v*)(qrow + (size_t)(i2 * 32 + 16) * 8);
        }
        short8v a2v0 = *(const short8v*)(vptr + i2 * 512);
        short8v a2v1 = *(const short8v*)(vptr + 1 * 128 * 512 + i2 * 512);
        short8v a2v2 = *(const short8v*)(vptr + 2 * 128 * 512 + i2 * 512);
        short8v a2v3 = *(const short8v*)(vptr + 3 * 128 * 512 + i2 * 512);

        // exp + L + pack + write Pb[itn&1]
        float p[8];
        #pragma unroll
        for (int j = 0; j < 4; ++j) { p[j] = __expf(s0[j]); p[4 + j] = __expf(s1[j]); }
        #pragma unroll
        for (int j = 0; j < 8; ++j) Lacc += p[j];
        unsigned pk0 = pack2_rte(p[0], p[1]), pk1 = pack2_rte(p[2], p[3]);
        unsigned pk2 = pack2_rte(p[4], p[5]), pk3 = pack2_rte(p[6], p[7]);
        *(uint2*)&sm.Pb[w][itn & 1][l15][quad * 4]      = make_uint2(pk0, pk1);
        *(uint2*)&sm.Pb[w][itn & 1][l15][16 + quad * 4] = make_uint2(pk2, pk3);

        // ---- B-stream tail: PV(it) — bp already in flight, writes may
        // remain outstanding (lgkmcnt(2)), decoupled from the exp chain
        acc[0] = __builtin_amdgcn_mfma_f32_16x16x32_bf16(av0, bp, acc[0], 0, 0, 0);
        acc[1] = __builtin_amdgcn_mfma_f32_16x16x32_bf16(av1, bp, acc[1], 0, 0, 0);
        acc[2] = __builtin_amdgcn_mfma_f32_16x16x32_bf16(av2, bp, acc[2], 0, 0, 0);
        acc[3] = __builtin_amdgcn_mfma_f32_16x16x32_bf16(av3, bp, acc[3], 0, 0, 0);

        // rotate prefetch regs
        av0 = avn0; av1 = avn1; av2 = avn2; av3 = avn3;
        avn0 = a2v0; avn1 = a2v1; avn2 = a2v2; avn3 = a2v3;
        aqn0 = a2q0; aqn1 = a2q1;
    }

    // ---- epilog: PV for chunk 31 (buf 31&1 = 1)
    {
        short8v bp = *(const short8v*)&sm.Pb[w][1][l15][quad * 8];
        acc[0] = __builtin_amdgcn_mfma_f32_16x16x32_bf16(av0, bp, acc[0], 0, 0, 0);
        acc[1] = __builtin_amdgcn_mfma_f32_16x16x32_bf16(av1, bp, acc[1], 0, 0, 0);
        acc[2] = __builtin_amdgcn_mfma_f32_16x16x32_bf16(av2, bp, acc[2], 0, 0, 0);
        acc[3] = __builtin_amdgcn_mfma_f32_16x16x32_bf16(av3, bp, acc[3], 0, 0, 0);
    }

    // ---- L: combine quads within wave
    Lacc += __shfl_xor(Lacc, 16, 64);
    Lacc += __shfl_xor(Lacc, 32, 64);
    if (lane < 16) Lred[w][lane] = Lacc;

    // ---- barrier: all waves done reading Pb before Ored aliases it
    __syncthreads();

    #pragma unroll
    for (int ct = 0; ct < 4; ++ct)
        #pragma unroll
        for (int r = 0; r < 4; ++r)
            sm.Ored[w][ct * 16 + quad * 4 + r][l15] = acc[ct][r];
    if (t < 16)
        Lf[t] = 1.f / (Lred[0][t] + Lred[1][t] + Lred[2][t] + Lred[3][t]);
    __syncthreads();

    // ---- fused epilogue: gamma * O / L + x
    {
        const float gv = gamma[0];
        int c = t >> 2, m4 = (t & 3) * 4;
        float4 o;
        #pragma unroll
        for (int i = 0; i < 4; ++i) {
            float s = sm.Ored[0][c][m4 + i] + sm.Ored[1][c][m4 + i]
                    + sm.Ored[2][c][m4 + i] + sm.Ored[3][c][m4 + i];
            ((float*)&o)[i] = s * Lf[m4 + i];
        }
        size_t gbase = (size_t)(b * 64 + c) * NN + m0 + m4;
        float4 xv = *(const float4*)&x[gbase];
        float4 r;
        r.x = gv * o.x + xv.x; r.y = gv * o.y + xv.y;
        r.z = gv * o.z + xv.z; r.w = gv * o.w + xv.w;
        *(float4*)&out[gbase] = r;
    }
}

extern "C" void kernel_launch(void* const* d_in, const int* in_sizes, int n_in,
                              void* d_out, int out_size, void* d_ws, size_t ws_size,
                              hipStream_t stream) {
    const float* x     = (const float*)d_in[0];
    const float* Wq    = (const float*)d_in[1];
    const float* Wk    = (const float*)d_in[2];
    const float* Wv    = (const float*)d_in[3];
    const float* gamma = (const float*)d_in[4];
    float* out = (float*)d_out;

    unsigned short* ws = (unsigned short*)d_ws;
    unsigned short* Qt  = ws;                        // [B][N][8]  bf16, 256 KB
    unsigned short* Kt  = Qt + (size_t)BB * NN * 8;  // [B][N][8]  bf16, 256 KB
    unsigned short* Vsw = Kt + (size_t)BB * NN * 8;  // [B][4][128][512] bf16, 2 MB

    qkv_kernel<<<dim3(NN / 32, BB), 256, 0, stream>>>(x, Wq, Wk, Wv, Qt, Kt, Vsw);
    attn_kernel<<<dim3(NN / 16, BB), 256, 0, stream>>>(Qt, Kt, Vsw, x, gamma, out);
}